// Round 1
// 321.871 us; speedup vs baseline: 1.1739x; 1.1739x over previous
//
#include <hip/hip_runtime.h>

// Triangle multiplication (outgoing), B=1 N=512 CZ=128 C=16, f32 I/O.
// K0 pack weights f32->bf16 -> K1 proj GEMM (a,b,g; bf16 intermediates, LDS-W version)
// -> K2 per-channel 512^3 bf16 GEMMs (z, f32) -> K3 LN+matvec+gate (f32 out).

#define NN 512
#define PP (NN*NN)        // 262144
#define CZD 128
#define CD 16
#define LN_EPS 1e-5f

typedef unsigned short u16;
typedef __bf16 bf16x8 __attribute__((ext_vector_type(8)));
typedef float  f32x4  __attribute__((ext_vector_type(4)));

// ws layout (bytes)
#define OFF_A  0u           // a planes: 16 x P x bf16 = 8 MB
#define OFF_B  8388608u     // b planes: 8 MB
#define OFF_Z  16777216u    // z: 16 x P x f32 = 16 MB
#define OFF_G  33554432u    // g: P x 128 x bf16 = 64 MB
#define OFF_WT 100663296u   // packed Wt[192][128] bf16
#define OFF_BC 100712448u   // bias cat [192] f32

__device__ __forceinline__ float bf2f(u16 u) {
    union { unsigned int i; float f; } v; v.i = ((unsigned int)u) << 16; return v.f;
}
__device__ __forceinline__ u16 f2bf(float f) {  // RNE
    union { float f; unsigned int i; } v; v.f = f;
    unsigned int r = (v.i + 0x7FFFu + ((v.i >> 16) & 1u)) >> 16;
    return (u16)r;
}
__device__ __forceinline__ float sigmoidf(float x) { return 1.0f / (1.0f + __expf(-x)); }

// Uniform swizzled-LDS addressing: every proj LDS tile uses a 256B row stride
// with the XOR-16B swizzle (G4). Bijective within a row; 8B/16B alignment kept.
__device__ __forceinline__ int swz(int row, int bytecol) {
    return row * 256 + (bytecol ^ ((row & 7) << 4));
}

// ---------------- K0: pack Wt[192][128] bf16 (row n holds W[:,n]) + bias[192] f32
__global__ void pack_w(const float* __restrict__ Wa1, const float* __restrict__ Wa2,
                       const float* __restrict__ Wb1, const float* __restrict__ Wb2,
                       const float* __restrict__ Wg,
                       const float* __restrict__ ba1, const float* __restrict__ ba2,
                       const float* __restrict__ bb1, const float* __restrict__ bb2,
                       const float* __restrict__ bg,
                       u16* __restrict__ wt, float* __restrict__ bc) {
    int idx = blockIdx.x * 256 + threadIdx.x;           // 0..24575
    int n = idx >> 7, k = idx & 127;
    float v;
    if      (n < 16) v = Wa1[k * CD + n];
    else if (n < 32) v = Wa2[k * CD + (n - 16)];
    else if (n < 48) v = Wb1[k * CD + (n - 32)];
    else if (n < 64) v = Wb2[k * CD + (n - 48)];
    else             v = Wg [k * CZD + (n - 64)];
    wt[n * CZD + k] = f2bf(v);
    if (idx < 192) {
        float b;
        if      (idx < 16) b = ba1[idx];
        else if (idx < 32) b = ba2[idx - 16];
        else if (idx < 48) b = bb1[idx - 32];
        else if (idx < 64) b = bb2[idx - 48];
        else               b = bg [idx - 64];
        bc[idx] = b;
    }
}

// ---------------- K1: X[P,128] @ Wcat[128,192] with fused sigmoid epilogue.
// v2: 512 threads (8 waves), 128 rows/block, W in LDS (48KB, swizzled) so no
// AGPR-resident B fragments (occupancy 2 blocks/CU = 16 waves). Wave w owns row
// strip w*16..w*16+15 x all 192 cols (12 coltiles). Epilogue transposes a/b/g
// through reused LDS and stores fully coalesced (1KB/instr).
__global__ __launch_bounds__(512, 4) void proj_kernel(const float* __restrict__ x,
                                                      const u16* __restrict__ wt,
                                                      const float* __restrict__ bc,
                                                      u16* __restrict__ a_ws, u16* __restrict__ b_ws,
                                                      u16* __restrict__ g_ws) {
    extern __shared__ __align__(16) char lds[];         // 81920 B dynamic
    char* Wl = lds;                                     // [0, 48K): W 192 rows x 256B
    char* Xl = lds + 49152;                             // [48K, 80K): X 128 rows x 256B (bf16)
    char* aT = lds;                                     // epilogue reuse: 16 rows x 256B
    char* bT = lds + 4096;                              // 16 rows x 256B
    char* gT = lds + 49152;                             // 128 rows x 256B
    const int t = threadIdx.x;
    const int wv = t >> 6, lane = t & 63, l16 = lane & 15, quad = lane >> 4;
    const long pos0 = (long)blockIdx.x * 128;

    // stage W: 192 rows x 16 granules(16B) = 3072 chunks, 6/thread, coalesced 16B loads
#pragma unroll
    for (int i = 0; i < 6; ++i) {
        int c = t + 512 * i;
        int n = c >> 4, g = c & 15;
        uint4 v = *reinterpret_cast<const uint4*>(wt + n * CZD + g * 8);
        *reinterpret_cast<uint4*>(Wl + swz(n, g * 16)) = v;
    }
    // stage X: 128 rows x 32 float4 = 4096 chunks, 8/thread; f32 -> bf16 on the fly
#pragma unroll
    for (int i = 0; i < 8; ++i) {
        int c = t + 512 * i;
        int r = c >> 5, c4 = c & 31;
        const float4 v = *reinterpret_cast<const float4*>(x + (pos0 + r) * CZD + c4 * 4);
        u16 tmp[4] = { f2bf(v.x), f2bf(v.y), f2bf(v.z), f2bf(v.w) };
        *reinterpret_cast<uint2*>(Xl + swz(r, c4 * 8)) = *reinterpret_cast<const uint2*>(tmp);
    }
    __syncthreads();

    f32x4 acc[12];
#pragma unroll
    for (int ct = 0; ct < 12; ++ct) acc[ct] = (f32x4){0.f, 0.f, 0.f, 0.f};
    bf16x8 af[4];
#pragma unroll
    for (int ks = 0; ks < 4; ++ks)
        af[ks] = *reinterpret_cast<const bf16x8*>(Xl + swz(wv * 16 + l16, ks * 64 + quad * 16));
#pragma unroll
    for (int ks = 0; ks < 4; ++ks)
#pragma unroll
        for (int ct = 0; ct < 12; ++ct) {
            bf16x8 wb = *reinterpret_cast<const bf16x8*>(Wl + swz(ct * 16 + l16, ks * 64 + quad * 16));
            acc[ct] = __builtin_amdgcn_mfma_f32_16x16x32_bf16(af[ks], wb, acc[ct], 0, 0, 0);
        }
    __syncthreads();                                    // all waves done reading Wl/Xl

    // epilogue: sigmoid + transpose into LDS
    {
        const float ba1 = bc[l16], ba2 = bc[16 + l16], bb1 = bc[32 + l16], bb2 = bc[48 + l16];
        u16 av[4], bv[4];
#pragma unroll
        for (int r = 0; r < 4; ++r) {
            av[r] = f2bf(sigmoidf((acc[0][r] + ba1) * (acc[1][r] + ba2)));
            bv[r] = f2bf(sigmoidf((acc[2][r] + bb1) * (acc[3][r] + bb2)));
        }
        // aT/bT row = channel (l16), col = pos*2; 4 consecutive pos pack into one 8B write
        *reinterpret_cast<uint2*>(aT + swz(l16, wv * 32 + quad * 8)) = *reinterpret_cast<const uint2*>(av);
        *reinterpret_cast<uint2*>(bT + swz(l16, wv * 32 + quad * 8)) = *reinterpret_cast<const uint2*>(bv);
        // gT row = pos, col = ch*2 (matches global [pos][128ch] layout)
#pragma unroll
        for (int ct = 0; ct < 8; ++ct) {
            const float bgv = bc[64 + ct * 16 + l16];
#pragma unroll
            for (int r = 0; r < 4; ++r) {
                int pos = wv * 16 + quad * 4 + r;
                *reinterpret_cast<u16*>(gT + swz(pos, ct * 32 + l16 * 2)) =
                    f2bf(sigmoidf(acc[4 + ct][r] + bgv));
            }
        }
    }
    __syncthreads();

    // coalesced write-out: aT/bT 4KB each (16 ch x 128 pos u16), gT 32KB
    if (t < 256) {
        int ch = t >> 4, i = t & 15;
        uint4 v = *reinterpret_cast<const uint4*>(aT + swz(ch, i * 16));
        *reinterpret_cast<uint4*>(a_ws + (long)ch * PP + pos0 + i * 8) = v;   // 256B runs/plane
    } else {
        int u = t - 256;
        int ch = u >> 4, i = u & 15;
        uint4 v = *reinterpret_cast<const uint4*>(bT + swz(ch, i * 16));
        *reinterpret_cast<uint4*>(b_ws + (long)ch * PP + pos0 + i * 8) = v;
    }
#pragma unroll
    for (int i = 0; i < 4; ++i) {
        int c = t + 512 * i;                             // 2048 = 128 pos x 16 granules
        int pos = c >> 4, g = c & 15;
        uint4 v = *reinterpret_cast<const uint4*>(gT + swz(pos, g * 16));
        *reinterpret_cast<uint4*>(g_ws + (pos0 + pos) * CZD + g * 8) = v;     // 4 full pos rows/instr
    }
}

// ---------------- K2: per-channel Z_c = A_c @ B_c (512x512x512), 64x64 tile, BK=64.
// B staged transposed into LDS with XOR swizzle: chunk (j, kc) stored at col (kc ^ (j&7))*8.
__global__ __launch_bounds__(256) void tri_kernel(const u16* __restrict__ a_ws,
                                                  const u16* __restrict__ b_ws,
                                                  float* __restrict__ z_ws) {
    __shared__ __align__(16) u16 Alds[64][72];          // stride 144B: 16B-aligned, 2-way banks (free)
    __shared__ __align__(16) u16 Btl[64][72];
    const int t = threadIdx.x;
    const int wave = t >> 6, lane = t & 63, l16 = lane & 15, quad = lane >> 4;
    const int c = blockIdx.y;
    const int i0 = (blockIdx.x >> 3) * 64, j0 = (blockIdx.x & 7) * 64;
    const u16* Ap = a_ws + (long)c * PP;
    const u16* Bp = b_ws + (long)c * PP;

    f32x4 acc[4];
#pragma unroll
    for (int ct = 0; ct < 4; ++ct) acc[ct] = (f32x4){0.f, 0.f, 0.f, 0.f};

    for (int k0 = 0; k0 < NN; k0 += 64) {
        // A tile: 64 rows x 64 k, row-wise 16B loads
#pragma unroll
        for (int i = 0; i < 2; ++i) {
            int chunk = t + 256 * i;
            int r = chunk >> 3, ko = (chunk & 7) << 3;
            uint4 v = *reinterpret_cast<const uint4*>(Ap + (long)(i0 + r) * NN + k0 + ko);
            *reinterpret_cast<uint4*>(&Alds[r][ko]) = v;
        }
        // B tile transposed: thread owns (j, kgroup): 8 column loads, one 16B LDS write
#pragma unroll
        for (int i = 0; i < 2; ++i) {
            int chunk = t + 256 * i;
            int j = chunk & 63, kg = chunk >> 6;
            u16 tmp[8];
#pragma unroll
            for (int kk = 0; kk < 8; ++kk)
                tmp[kk] = Bp[(long)(k0 + kg * 8 + kk) * NN + j0 + j];
            *reinterpret_cast<uint4*>(&Btl[j][(kg ^ (j & 7)) << 3]) = *reinterpret_cast<uint4*>(tmp);
        }
        __syncthreads();
#pragma unroll
        for (int kk = 0; kk < 64; kk += 32) {
            bf16x8 af = *reinterpret_cast<const bf16x8*>(&Alds[wave * 16 + l16][kk + quad * 8]);
            int kc = (kk >> 3) + quad;                  // k-chunk index 0..7
#pragma unroll
            for (int ct = 0; ct < 4; ++ct) {
                int n = ct * 16 + l16;
                bf16x8 bfv = *reinterpret_cast<const bf16x8*>(&Btl[n][(kc ^ (n & 7)) << 3]);
                acc[ct] = __builtin_amdgcn_mfma_f32_16x16x32_bf16(af, bfv, acc[ct], 0, 0, 0);
            }
        }
        __syncthreads();
    }
    float* Zp = z_ws + (long)c * PP;
#pragma unroll
    for (int ct = 0; ct < 4; ++ct)
#pragma unroll
        for (int r = 0; r < 4; ++r)
            Zp[(long)(i0 + wave * 16 + quad * 4 + r) * NN + j0 + ct * 16 + l16] = acc[ct][r];
}

// ---------------- K3: out[pos][cz] = g[pos][cz] * (LN(z[pos][:]) @ Wz + bz)[cz], f32 out
__global__ __launch_bounds__(256) void out_kernel(const float* __restrict__ z_ws,
                                                  const u16* __restrict__ g_ws,
                                                  const float* __restrict__ Wz, const float* __restrict__ bz,
                                                  const float* __restrict__ lng, const float* __restrict__ lnb,
                                                  float* __restrict__ out) {
    __shared__ __align__(16) float zt[16][72];
    __shared__ __align__(16) float nl[64][20];
    __shared__ __align__(16) float wz[16][128];
    __shared__ float bzl[128];
    __shared__ float lg[16], lb[16];
    const int t = threadIdx.x;
    const long pos0 = (long)blockIdx.x * 64;

    {   // stage z: 16 channel-planes x 64 consecutive positions, coalesced float4
        int cc = t >> 4, off = (t & 15) << 2;
        const float4 v = *reinterpret_cast<const float4*>(z_ws + (long)cc * PP + pos0 + off);
        *reinterpret_cast<float4*>(&zt[cc][off]) = v;
    }
#pragma unroll
    for (int i = 0; i < 8; ++i) {
        int idx = t + 256 * i;                           // 2048 = 16*128
        wz[idx >> 7][idx & 127] = Wz[idx];
    }
    if (t < 128)      bzl[t] = bz[t];
    else if (t < 144) lg[t - 128] = lng[t - 128];
    else if (t < 160) lb[t - 144] = lnb[t - 144];
    __syncthreads();

    {   // LN over 16 channels; thread (p = t&63, cgr = t>>6) normalizes 4 channels
        int p = t & 63, cgr = t >> 6;
        float m = 0.f;
#pragma unroll
        for (int c0 = 0; c0 < 16; ++c0) m += zt[c0][p];
        m *= (1.f / 16.f);
        float v = 0.f;
#pragma unroll
        for (int c0 = 0; c0 < 16; ++c0) { float d = zt[c0][p] - m; v += d * d; }
        v *= (1.f / 16.f);
        float s = rsqrtf(v + LN_EPS);
#pragma unroll
        for (int cc = 0; cc < 4; ++cc) {
            int c0 = cgr * 4 + cc;
            nl[p][c0] = (zt[c0][p] - m) * s * lg[c0] + lb[c0];
        }
    }
    __syncthreads();

    const int cz = t & 127, pg = t >> 7;
    float wzr[16];
#pragma unroll
    for (int c0 = 0; c0 < 16; ++c0) wzr[c0] = wz[c0][cz];
    const float bzv = bzl[cz];
#pragma unroll
    for (int pp2 = 0; pp2 < 32; ++pp2) {
        int p = pg * 32 + pp2;
        const float4* np = reinterpret_cast<const float4*>(&nl[p][0]);
        float y = bzv;
#pragma unroll
        for (int c4 = 0; c4 < 4; ++c4) {
            float4 nv = np[c4];
            y += nv.x * wzr[c4 * 4 + 0] + nv.y * wzr[c4 * 4 + 1] +
                 nv.z * wzr[c4 * 4 + 2] + nv.w * wzr[c4 * 4 + 3];
        }
        long o = (pos0 + p) * CZD + cz;
        float gv = bf2f(g_ws[o]);
        out[o] = gv * y;
    }
}

extern "C" void kernel_launch(void* const* d_in, const int* in_sizes, int n_in,
                              void* d_out, int out_size, void* d_ws, size_t ws_size,
                              hipStream_t stream) {
    const float* x   = (const float*)d_in[0];
    const float* Wa1 = (const float*)d_in[1];
    const float* ba1 = (const float*)d_in[2];
    const float* Wa2 = (const float*)d_in[3];
    const float* ba2 = (const float*)d_in[4];
    const float* Wb1 = (const float*)d_in[5];
    const float* bb1 = (const float*)d_in[6];
    const float* Wb2 = (const float*)d_in[7];
    const float* bb2 = (const float*)d_in[8];
    const float* lng = (const float*)d_in[9];
    const float* lnb = (const float*)d_in[10];
    const float* Wg  = (const float*)d_in[11];
    const float* bg  = (const float*)d_in[12];
    const float* Wz  = (const float*)d_in[13];
    const float* bz  = (const float*)d_in[14];
    float* out = (float*)d_out;
    char* ws = (char*)d_ws;
    u16*   a_ws = (u16*)(ws + OFF_A);
    u16*   b_ws = (u16*)(ws + OFF_B);
    float* z_ws = (float*)(ws + OFF_Z);
    u16*   g_ws = (u16*)(ws + OFF_G);
    u16*   wt   = (u16*)(ws + OFF_WT);
    float* bc   = (float*)(ws + OFF_BC);

    hipLaunchKernelGGL(pack_w, dim3(96), dim3(256), 0, stream,
                       Wa1, Wa2, Wb1, Wb2, Wg, ba1, ba2, bb1, bb2, bg, wt, bc);
    hipLaunchKernelGGL(proj_kernel, dim3(2048), dim3(512), 81920, stream, x, wt, bc, a_ws, b_ws, g_ws);
    hipLaunchKernelGGL(tri_kernel, dim3(64, 16), dim3(256), 0, stream, a_ws, b_ws, z_ws);
    hipLaunchKernelGGL(out_kernel, dim3(4096), dim3(256), 0, stream, z_ws, g_ws, Wz, bz, lng, lnb, out);
}